// Round 19
// baseline (73.612 us; speedup 1.0000x reference)
//
#include <hip/hip_runtime.h>
#include <hip/hip_bf16.h>
#include <math.h>

#define N_   4096
#define DIN  512
#define D_   64

typedef __attribute__((ext_vector_type(8))) short  bf16x8;
typedef __attribute__((ext_vector_type(4))) float  f32x4;

#define ZERO4 ((f32x4){0.f, 0.f, 0.f, 0.f})

__device__ __forceinline__ unsigned short bf16rne(float x) {
    unsigned u = __float_as_uint(x);
    return (unsigned short)((u + 0x7FFFu + ((u >> 16) & 1u)) >> 16);
}
__device__ __forceinline__ unsigned cvt2(float a, float b) {
    __hip_bfloat162 h = __float22bfloat162_rn(make_float2(a, b));
    unsigned u; __builtin_memcpy(&u, &h, 4);
    return u;
}
__device__ __forceinline__ uint2 cvt4(float4 v) {
    return make_uint2(cvt2(v.x, v.y), cvt2(v.z, v.w));
}
// VALU cross-lane half-swaps (gfx950)
__device__ __forceinline__ void pl32swap(unsigned &a, unsigned &b) {
    asm volatile("v_permlane32_swap_b32 %0, %1" : "+v"(a), "+v"(b));
}
__device__ __forceinline__ void pl16swap(unsigned &a, unsigned &b) {
    asm volatile("v_permlane16_swap_b32 %0, %1" : "+v"(a), "+v"(b));
}
// XOR-swizzled short-index for [row][128B] tiles: byte_in_row ^ ((row&7)<<4)
__device__ __forceinline__ int swz(int row, int byte_in_row) {
    return (row * 128 + (byte_in_row ^ ((row & 7) << 4))) >> 1;
}

// async 16B global->LDS (linear LDS dest = wave base + lane*16)
#define GLD16(gp, lp)                                                          \
    __builtin_amdgcn_global_load_lds(                                          \
        (const __attribute__((address_space(1))) unsigned int*)(gp),           \
        (__attribute__((address_space(3))) unsigned int*)(lp), 16, 0, 0)

// 64-row q-tiles, 4-chunk slices: slices(qi) = (qi>>2)+1 = g+1;
// prefix pb4(qi) = 2g(g+1) + r(g+1), g=qi>>2, r=qi&3; total 544 per batch
__device__ __forceinline__ int pb4(int qi) {
    const int g = qi >> 2, r = qi & 3;
    return 2 * g * (g + 1) + r * (g + 1);
}
#define PART64_F 4160   // 64*64 O + 64 l (floats)

#define SCQ 0.18033688f   // 0.125 * log2(e), folded into Q at projection

// ---------------------------------------------------------------------------
// Projection GEMM (R14-proven + Q prescale): X fp32 -> {K n-major bf16,
// Q n-major bf16 pre-scaled by 0.125*log2e, Vt o-major bf16}.
// 512 thr / 8 waves, BM=64, BK=64, LDS double-buffered, swizzled tiles.
// ---------------------------------------------------------------------------
__global__ __launch_bounds__(512) void proj_kernel(
    const float* __restrict__ X, const float* __restrict__ Wk,
    const float* __restrict__ Wq, const float* __restrict__ Wv,
    unsigned short* __restrict__ Kb, unsigned short* __restrict__ Qb,
    unsigned short* __restrict__ Vt)
{
    __shared__ unsigned short Xs[2][64 * 64];
    __shared__ unsigned short Ws[2][192 * 64];

    const int tid  = threadIdx.x;
    const int lane = tid & 63;
    const int w    = tid >> 6;
    const int q15  = lane & 15;
    const int hi   = lane >> 4;
    const int rt   = w >> 1;
    const int oh   = w & 1;
    const int rbase = blockIdx.x * 64;

    float4 xr[2], wr[6];

    auto loadT = [&](int kc) {
        #pragma unroll
        for (int i = 0; i < 2; ++i) {
            const int idx = tid + i * 512;
            xr[i] = *(const float4*)(X + (size_t)(rbase + (idx >> 4)) * DIN + kc + (idx & 15) * 4);
        }
        #pragma unroll
        for (int i = 0; i < 6; ++i) {
            const int idx  = tid + i * 512;
            const int wrow = idx >> 4;
            const float* Wp = (wrow < 64)  ? Wk + (size_t)wrow * DIN
                            : (wrow < 128) ? Wq + (size_t)(wrow - 64) * DIN
                                           : Wv + (size_t)(wrow - 128) * DIN;
            wr[i] = *(const float4*)(Wp + kc + (idx & 15) * 4);
        }
    };
    auto storeT = [&](int p) {
        #pragma unroll
        for (int i = 0; i < 2; ++i) {
            const int idx = tid + i * 512;
            *(uint2*)&Xs[p][swz(idx >> 4, (idx & 15) * 8)] = cvt4(xr[i]);
        }
        #pragma unroll
        for (int i = 0; i < 6; ++i) {
            const int idx = tid + i * 512;
            *(uint2*)&Ws[p][swz(idx >> 4, (idx & 15) * 8)] = cvt4(wr[i]);
        }
    };

    f32x4 acc[6];
    #pragma unroll
    for (int i = 0; i < 6; ++i) acc[i] = ZERO4;

    loadT(0);
    int p = 0;
    for (int it = 0; it < 8; ++it) {
        storeT(p);
        __syncthreads();
        if (it < 7) loadT((it + 1) * 64);
        #pragma unroll
        for (int ks = 0; ks < 2; ++ks) {
            bf16x8 af = *(const bf16x8*)&Xs[p][swz(rt * 16 + q15, ks * 64 + hi * 16)];
            #pragma unroll
            for (int j = 0; j < 6; ++j) {
                bf16x8 bfr = *(const bf16x8*)&Ws[p][swz((oh * 6 + j) * 16 + q15, ks * 64 + hi * 16)];
                acc[j] = __builtin_amdgcn_mfma_f32_16x16x32_bf16(af, bfr, acc[j], 0, 0, 0);
            }
        }
        p ^= 1;
    }

    unsigned short* Os = &Ws[0][0];               // [64n][66o] V staging scratch
    #pragma unroll
    for (int j = 0; j < 6; ++j) {
        const int og = oh * 6 + j;
        #pragma unroll
        for (int r = 0; r < 4; ++r) {
            const int n = rt * 16 + hi * 4 + r;
            const int o = og * 16 + q15;
            if (og < 4)      Kb[(size_t)(rbase + n) * D_ + o]        = bf16rne(acc[j][r]);
            else if (og < 8) Qb[(size_t)(rbase + n) * D_ + (o - 64)] = bf16rne(acc[j][r] * SCQ);
            else             Os[n * 66 + (o - 128)]                  = bf16rne(acc[j][r]);
        }
    }
    __syncthreads();
    {
        const int o  = tid >> 3;
        const int ng = (tid & 7) * 8;
        unsigned short tmp[8];
        #pragma unroll
        for (int i = 0; i < 8; ++i) tmp[i] = Os[(ng + i) * 66 + o];
        const int b  = rbase >> 12;
        const int nb = rbase & (N_ - 1);
        *(uint4*)(Vt + ((size_t)b * D_ + o) * N_ + nb + ng) = *(uint4*)&tmp[0];
    }
}

// ---------------------------------------------------------------------------
// Pass 1: partial attention. Block = 4 waves x 64 q-rows, k-slice <=4 chunks
// -> 2176 blocks (~8.5/CU of work). K staged via global_load_lds (double-
// buffered, ONE barrier/chunk); V-frags read DIRECT from global (o-major Vt,
// L2-resident 16-line gathers — halves the DS-pipe floor, LDS 16KB/block).
// V loads issue after QK^T, hidden under softmax. setprio around MFMA.
// In-register P via permlane. No-max softmax (Q pre-scaled) -> additive
// partials [64q][64d]+l[64].
// ---------------------------------------------------------------------------
__global__ __launch_bounds__(256) void attn_part_kernel(
    const unsigned short* __restrict__ Qb, const unsigned short* __restrict__ Kb,
    const unsigned short* __restrict__ Vt, float* __restrict__ Pws)
{
    __shared__ unsigned short Ks[2][64 * 64];     // [key][d] swizzled

    const int tid  = threadIdx.x;
    const int lane = tid & 63;
    const int w    = tid >> 6;
    const int q15  = lane & 15;
    const int hi   = lane >> 4;

    const int b = blockIdx.x & 3;                 // XCD-pinned batch
    const int u = blockIdx.x >> 2;                // 0..543
    const int v = 543 - u;                        // big q-tiles first
    int g = 0;
    #pragma unroll
    for (int t = 1; t < 16; ++t)
        if (2 * t * (t + 1) <= v) g = t;
    const int idx = v - 2 * g * (g + 1);
    const int qs  = idx / (g + 1);
    const int qi  = 4 * g + qs;                   // 0..63
    const int sl  = idx - qs * (g + 1);           // 0..g

    const int nch  = qi + 1;
    const int cbeg = sl * 4;
    const int cend = min(nch, cbeg + 4);
    const int qb   = qi * 64;

    const unsigned short* Qp = Qb + (size_t)b * N_ * D_;
    const unsigned short* Kp = Kb + (size_t)b * N_ * D_;
    const unsigned short* Vp = Vt + (size_t)b * D_ * N_;

    const int qg = qb + w * 16 + q15;             // this lane's q row
    bf16x8 qf[2];
    #pragma unroll
    for (int ks = 0; ks < 2; ++ks)
        qf[ks] = *(const bf16x8*)(Qp + (size_t)qg * D_ + ks * 32 + hi * 8);

    f32x4 accO[4];
    #pragma unroll
    for (int dt = 0; dt < 4; ++dt) accO[dt] = ZERO4;
    float lsum = 0.f;

    const int lsw = 8 * ((lane & 7) ^ (lane >> 3));

    auto issueChunk = [&](int p, int c) {         // K only (V is direct-global)
        const int kb2 = c * 64;
        #pragma unroll
        for (int i = 0; i < 2; ++i) {
            const int r8  = w * 2 + i;            // 8-row group 0..7
            const int row = r8 * 8 + (lane >> 3);
            GLD16(Kp + (size_t)(kb2 + row) * D_ + lsw, &Ks[p][r8 * 512]);
        }
    };

    issueChunk(0, cbeg);
    __syncthreads();                              // drains vmcnt + barrier

    int p = 0;
    for (int c = cbeg; c < cend; ++c) {
        if (c + 1 < cend) issueChunk(p ^ 1, c + 1);   // overlap with compute
        const int kbase = c * 64;
        const bool edge = (c == nch - 1);         // single diagonal chunk

        // QK^T (swapped): S^T[k][q]
        f32x4 sv[4];
        __builtin_amdgcn_s_setprio(1);
        #pragma unroll
        for (int kt = 0; kt < 4; ++kt) {
            bf16x8 k0 = *(const bf16x8*)&Ks[p][swz(kt * 16 + q15, hi * 16)];
            bf16x8 k1 = *(const bf16x8*)&Ks[p][swz(kt * 16 + q15, 64 + hi * 16)];
            sv[kt] = __builtin_amdgcn_mfma_f32_16x16x32_bf16(k0, qf[0], ZERO4, 0, 0, 0);
            sv[kt] = __builtin_amdgcn_mfma_f32_16x16x32_bf16(k1, qf[1], sv[kt], 0, 0, 0);
        }
        __builtin_amdgcn_s_setprio(0);

        // V frags direct from global (L2-resident); latency hides under softmax
        bf16x8 vf[2][4];
        #pragma unroll
        for (int ks2 = 0; ks2 < 2; ++ks2)
            #pragma unroll
            for (int dt = 0; dt < 4; ++dt)
                vf[ks2][dt] = *(const bf16x8*)(Vp + (size_t)(dt * 16 + q15) * N_
                                               + kbase + ks2 * 32 + hi * 8);

        // softmax-lite (Q pre-scaled: exp2 direct) -> packed pairs pk[kt][rp]
        unsigned pk[4][2];
        #pragma unroll
        for (int kt = 0; kt < 4; ++kt) {
            float pv[4];
            #pragma unroll
            for (int r = 0; r < 4; ++r) {
                float vv = sv[kt][r];
                const int kg = kbase + kt * 16 + hi * 4 + r;
                if (edge) vv = (kg <= qg) ? vv : -INFINITY;
                pv[r] = __builtin_amdgcn_exp2f(vv);
                lsum += pv[r];
            }
            pk[kt][0] = cvt2(pv[0], pv[1]);
            pk[kt][1] = cvt2(pv[2], pv[3]);
        }

        // redistribute to A-frag P[q=q15][k=ks2*32+hi*8+j] via permlane; PV
        #pragma unroll
        for (int ks2 = 0; ks2 < 2; ++ks2) {
            unsigned a0 = pk[2 * ks2][0],     a1 = pk[2 * ks2][1];
            unsigned b0 = pk[2 * ks2 + 1][0], b1 = pk[2 * ks2 + 1][1];
            pl32swap(a0, b0);
            pl32swap(a1, b1);
            pl16swap(a0, b0);
            pl16swap(a1, b1);
            unsigned pw[4] = {a0, a1, b0, b1};
            bf16x8 pa;
            __builtin_memcpy(&pa, pw, 16);
            __builtin_amdgcn_s_setprio(1);
            #pragma unroll
            for (int dt = 0; dt < 4; ++dt)
                accO[dt] = __builtin_amdgcn_mfma_f32_16x16x32_bf16(pa, vf[ks2][dt], accO[dt], 0, 0, 0);
            __builtin_amdgcn_s_setprio(0);
        }

        __syncthreads();                          // next K buffer staged
        p ^= 1;
    }

    // l reduce over hi groups
    lsum += __shfl_xor(lsum, 16);
    lsum += __shfl_xor(lsum, 32);

    // partial write: O [64q][64d]
    float* partO = Pws + ((size_t)b * 544 + pb4(qi) + sl) * PART64_F;
    #pragma unroll
    for (int dt = 0; dt < 4; ++dt)
        #pragma unroll
        for (int r = 0; r < 4; ++r)
            partO[(w * 16 + hi * 4 + r) * 64 + dt * 16 + q15] = accO[dt][r];
    if (hi == 0) partO[4096 + w * 16 + q15] = lsum;
}

// ---------------------------------------------------------------------------
// Pass 2: sum <=16 slice partials ([64q][64d], no transpose), normalize,
// write O. 256 blocks.
// ---------------------------------------------------------------------------
__global__ __launch_bounds__(256) void attn_merge_kernel(
    const float* __restrict__ Pws, float* __restrict__ O)
{
    const int tid = threadIdx.x;
    const int b   = blockIdx.x & 3;
    const int qi  = blockIdx.x >> 2;
    const int np  = (qi + 4) >> 2;                // ceil((qi+1)/4) <= 16
    const float* base = Pws + ((size_t)b * 544 + pb4(qi)) * PART64_F;

    const int q  = tid >> 2;                      // 0..63
    const int dg = (tid & 3) * 16;                // 0,16,32,48

    float s[16];
    #pragma unroll
    for (int i = 0; i < 16; ++i) s[i] = 0.f;
    float L = 0.f;
    for (int pp = 0; pp < np; ++pp) {
        const float* sp = base + (size_t)pp * PART64_F + q * 64 + dg;
        #pragma unroll
        for (int i = 0; i < 4; ++i) {
            float4 v = *(const float4*)(sp + i * 4);
            s[4*i]   += v.x; s[4*i+1] += v.y;
            s[4*i+2] += v.z; s[4*i+3] += v.w;
        }
        L += base[(size_t)pp * PART64_F + 4096 + q];
    }
    const float rL = 1.0f / L;
    float* dst = O + ((size_t)b * N_ + qi * 64 + q) * D_ + dg;
    #pragma unroll
    for (int i = 0; i < 4; ++i)
        *(float4*)(dst + i * 4) = make_float4(s[4*i] * rL, s[4*i+1] * rL,
                                              s[4*i+2] * rL, s[4*i+3] * rL);
}

// ---------------------------------------------------------------------------
extern "C" void kernel_launch(void* const* d_in, const int* in_sizes, int n_in,
                              void* d_out, int out_size, void* d_ws, size_t ws_size,
                              hipStream_t stream)
{
    const float* x  = (const float*)d_in[0];
    const float* Wk = (const float*)d_in[1];
    const float* Wq = (const float*)d_in[2];
    const float* Wv = (const float*)d_in[3];
    float* O = (float*)d_out;

    const size_t per = (size_t)4 * N_ * D_;       // 1M bf16 elements each
    unsigned short* Kb = (unsigned short*)d_ws;
    unsigned short* Qb = Kb + per;
    unsigned short* Vt = Qb + per;
    float* Pws = (float*)((char*)d_ws + 3 * per * sizeof(unsigned short));

    proj_kernel<<<dim3(4 * N_ / 64), 512, 0, stream>>>(x, Wk, Wq, Wv, Kb, Qb, Vt);
    attn_part_kernel<<<dim3(2176), 256, 0, stream>>>(Qb, Kb, Vt, Pws);
    attn_merge_kernel<<<dim3(256), 256, 0, stream>>>(Pws, O);
}

// Round 20
// 47.646 us; speedup vs baseline: 1.5450x; 1.5450x over previous
//
#include <hip/hip_runtime.h>
#include <hip/hip_bf16.h>
#include <math.h>

#define N_   4096
#define DIN  512
#define D_   64

typedef __attribute__((ext_vector_type(8))) short  bf16x8;
typedef __attribute__((ext_vector_type(4))) float  f32x4;

#define ZERO4 ((f32x4){0.f, 0.f, 0.f, 0.f})

__device__ __forceinline__ unsigned short bf16rne(float x) {
    unsigned u = __float_as_uint(x);
    return (unsigned short)((u + 0x7FFFu + ((u >> 16) & 1u)) >> 16);
}
__device__ __forceinline__ unsigned cvt2(float a, float b) {
    __hip_bfloat162 h = __float22bfloat162_rn(make_float2(a, b));
    unsigned u; __builtin_memcpy(&u, &h, 4);
    return u;
}
__device__ __forceinline__ uint2 cvt4(float4 v) {
    return make_uint2(cvt2(v.x, v.y), cvt2(v.z, v.w));
}
// VALU cross-lane half-swaps (gfx950)
__device__ __forceinline__ void pl32swap(unsigned &a, unsigned &b) {
    asm volatile("v_permlane32_swap_b32 %0, %1" : "+v"(a), "+v"(b));
}
__device__ __forceinline__ void pl16swap(unsigned &a, unsigned &b) {
    asm volatile("v_permlane16_swap_b32 %0, %1" : "+v"(a), "+v"(b));
}
// XOR-swizzled short-index for [row][128B] tiles: byte_in_row ^ ((row&7)<<4)
__device__ __forceinline__ int swz(int row, int byte_in_row) {
    return (row * 128 + (byte_in_row ^ ((row & 7) << 4))) >> 1;
}

// async 16B global->LDS (linear LDS dest = wave base + lane*16)
#define GLD16(gp, lp)                                                          \
    __builtin_amdgcn_global_load_lds(                                          \
        (const __attribute__((address_space(1))) unsigned int*)(gp),           \
        (__attribute__((address_space(3))) unsigned int*)(lp), 16, 0, 0)

// 64-row q-tiles, 8-chunk slices: slices(qi)=ceil((qi+1)/8)=g+1 (g=qi>>3);
// prefix pb8(qi) = 4g(g+1) + r(g+1), r=qi&7; total 288 per batch
__device__ __forceinline__ int pb8(int qi) {
    const int g = qi >> 3, r = qi & 7;
    return 4 * g * (g + 1) + r * (g + 1);
}
#define PARTO_E 4096      // bf16 elements per partial O slab (64q x 64d)
#define PARTL_E 64        // fp32 l per slab

#define SCQ 0.18033688f   // 0.125 * log2(e), folded into Q at projection

// ---------------------------------------------------------------------------
// Projection GEMM (R14-proven + Q prescale): X fp32 -> {K n-major bf16,
// Q n-major bf16 pre-scaled by 0.125*log2e, Vt o-major bf16}.
// 512 thr / 8 waves, BM=64, BK=64, LDS double-buffered, swizzled tiles.
// ---------------------------------------------------------------------------
__global__ __launch_bounds__(512) void proj_kernel(
    const float* __restrict__ X, const float* __restrict__ Wk,
    const float* __restrict__ Wq, const float* __restrict__ Wv,
    unsigned short* __restrict__ Kb, unsigned short* __restrict__ Qb,
    unsigned short* __restrict__ Vt)
{
    __shared__ unsigned short Xs[2][64 * 64];
    __shared__ unsigned short Ws[2][192 * 64];

    const int tid  = threadIdx.x;
    const int lane = tid & 63;
    const int w    = tid >> 6;
    const int q15  = lane & 15;
    const int hi   = lane >> 4;
    const int rt   = w >> 1;
    const int oh   = w & 1;
    const int rbase = blockIdx.x * 64;

    float4 xr[2], wr[6];

    auto loadT = [&](int kc) {
        #pragma unroll
        for (int i = 0; i < 2; ++i) {
            const int idx = tid + i * 512;
            xr[i] = *(const float4*)(X + (size_t)(rbase + (idx >> 4)) * DIN + kc + (idx & 15) * 4);
        }
        #pragma unroll
        for (int i = 0; i < 6; ++i) {
            const int idx  = tid + i * 512;
            const int wrow = idx >> 4;
            const float* Wp = (wrow < 64)  ? Wk + (size_t)wrow * DIN
                            : (wrow < 128) ? Wq + (size_t)(wrow - 64) * DIN
                                           : Wv + (size_t)(wrow - 128) * DIN;
            wr[i] = *(const float4*)(Wp + kc + (idx & 15) * 4);
        }
    };
    auto storeT = [&](int p) {
        #pragma unroll
        for (int i = 0; i < 2; ++i) {
            const int idx = tid + i * 512;
            *(uint2*)&Xs[p][swz(idx >> 4, (idx & 15) * 8)] = cvt4(xr[i]);
        }
        #pragma unroll
        for (int i = 0; i < 6; ++i) {
            const int idx = tid + i * 512;
            *(uint2*)&Ws[p][swz(idx >> 4, (idx & 15) * 8)] = cvt4(wr[i]);
        }
    };

    f32x4 acc[6];
    #pragma unroll
    for (int i = 0; i < 6; ++i) acc[i] = ZERO4;

    loadT(0);
    int p = 0;
    for (int it = 0; it < 8; ++it) {
        storeT(p);
        __syncthreads();
        if (it < 7) loadT((it + 1) * 64);
        #pragma unroll
        for (int ks = 0; ks < 2; ++ks) {
            bf16x8 af = *(const bf16x8*)&Xs[p][swz(rt * 16 + q15, ks * 64 + hi * 16)];
            #pragma unroll
            for (int j = 0; j < 6; ++j) {
                bf16x8 bfr = *(const bf16x8*)&Ws[p][swz((oh * 6 + j) * 16 + q15, ks * 64 + hi * 16)];
                acc[j] = __builtin_amdgcn_mfma_f32_16x16x32_bf16(af, bfr, acc[j], 0, 0, 0);
            }
        }
        p ^= 1;
    }

    unsigned short* Os = &Ws[0][0];               // [64n][66o] V staging scratch
    #pragma unroll
    for (int j = 0; j < 6; ++j) {
        const int og = oh * 6 + j;
        #pragma unroll
        for (int r = 0; r < 4; ++r) {
            const int n = rt * 16 + hi * 4 + r;
            const int o = og * 16 + q15;
            if (og < 4)      Kb[(size_t)(rbase + n) * D_ + o]        = bf16rne(acc[j][r]);
            else if (og < 8) Qb[(size_t)(rbase + n) * D_ + (o - 64)] = bf16rne(acc[j][r] * SCQ);
            else             Os[n * 66 + (o - 128)]                  = bf16rne(acc[j][r]);
        }
    }
    __syncthreads();
    {
        const int o  = tid >> 3;
        const int ng = (tid & 7) * 8;
        unsigned short tmp[8];
        #pragma unroll
        for (int i = 0; i < 8; ++i) tmp[i] = Os[(ng + i) * 66 + o];
        const int b  = rbase >> 12;
        const int nb = rbase & (N_ - 1);
        *(uint4*)(Vt + ((size_t)b * D_ + o) * N_ + nb + ng) = *(uint4*)&tmp[0];
    }
}

// ---------------------------------------------------------------------------
// Pass 1 (R18-proven): Block = 4 waves x 64 q-rows, k-slice <=8 chunks ->
// 1152 blocks. K/V via global_load_lds (linear dest, inverse-swizzled
// source), double-buffered, ONE barrier/chunk. In-register P via permlane.
// No-max softmax (Q pre-scaled) -> additive partials, O slab in BF16
// (halves merge traffic), l in fp32.
// ---------------------------------------------------------------------------
__global__ __launch_bounds__(256) void attn_part_kernel(
    const unsigned short* __restrict__ Qb, const unsigned short* __restrict__ Kb,
    const unsigned short* __restrict__ Vt, unsigned short* __restrict__ PwsO,
    float* __restrict__ PwsL)
{
    __shared__ unsigned short Ks[2][64 * 64];     // [key][d] swizzled
    __shared__ unsigned short Vs[2][64 * 64];     // [d][key] swizzled

    const int tid  = threadIdx.x;
    const int lane = tid & 63;
    const int w    = tid >> 6;
    const int q15  = lane & 15;
    const int hi   = lane >> 4;

    const int b = blockIdx.x & 3;                 // XCD-pinned batch
    const int u = blockIdx.x >> 2;                // 0..287
    const int v = 287 - u;                        // big q-tiles first
    int g = 0;
    #pragma unroll
    for (int t = 1; t < 8; ++t)
        if (4 * t * (t + 1) <= v) g = t;
    const int idx = v - 4 * g * (g + 1);
    const int qs  = idx / (g + 1);
    const int qi  = 8 * g + qs;                   // 0..63
    const int sl  = idx - qs * (g + 1);           // 0..g

    const int nch  = qi + 1;
    const int cbeg = sl * 8;
    const int cend = min(nch, cbeg + 8);
    const int qb   = qi * 64;

    const unsigned short* Qp = Qb + (size_t)b * N_ * D_;
    const unsigned short* Kp = Kb + (size_t)b * N_ * D_;
    const unsigned short* Vp = Vt + (size_t)b * D_ * N_;

    const int qg = qb + w * 16 + q15;             // this lane's q row
    bf16x8 qf[2];
    #pragma unroll
    for (int ks = 0; ks < 2; ++ks)
        qf[ks] = *(const bf16x8*)(Qp + (size_t)qg * D_ + ks * 32 + hi * 8);

    f32x4 accO[4];
    #pragma unroll
    for (int dt = 0; dt < 4; ++dt) accO[dt] = ZERO4;
    float lsum = 0.f;

    const int lsw = 8 * ((lane & 7) ^ (lane >> 3));

    auto issueChunk = [&](int p, int c) {
        const int kb2 = c * 64;
        #pragma unroll
        for (int i = 0; i < 2; ++i) {
            const int r8  = w * 2 + i;            // 8-row group 0..7
            const int row = r8 * 8 + (lane >> 3);
            GLD16(Kp + (size_t)(kb2 + row) * D_ + lsw, &Ks[p][r8 * 512]);
            GLD16(Vp + (size_t)row * N_ + kb2 + lsw,   &Vs[p][r8 * 512]);
        }
    };

    issueChunk(0, cbeg);
    __syncthreads();                              // drains vmcnt + barrier

    int p = 0;
    for (int c = cbeg; c < cend; ++c) {
        if (c + 1 < cend) issueChunk(p ^ 1, c + 1);   // overlap with compute
        const int kbase = c * 64;
        const bool edge = (c == nch - 1);         // single diagonal chunk

        // QK^T (swapped): S^T[k][q]
        f32x4 sv[4];
        #pragma unroll
        for (int kt = 0; kt < 4; ++kt) {
            bf16x8 k0 = *(const bf16x8*)&Ks[p][swz(kt * 16 + q15, hi * 16)];
            bf16x8 k1 = *(const bf16x8*)&Ks[p][swz(kt * 16 + q15, 64 + hi * 16)];
            sv[kt] = __builtin_amdgcn_mfma_f32_16x16x32_bf16(k0, qf[0], ZERO4, 0, 0, 0);
            sv[kt] = __builtin_amdgcn_mfma_f32_16x16x32_bf16(k1, qf[1], sv[kt], 0, 0, 0);
        }

        // softmax-lite (Q pre-scaled: exp2 direct) -> packed pairs pk[kt][rp]
        unsigned pk[4][2];
        #pragma unroll
        for (int kt = 0; kt < 4; ++kt) {
            float pv[4];
            #pragma unroll
            for (int r = 0; r < 4; ++r) {
                float vv = sv[kt][r];
                const int kg = kbase + kt * 16 + hi * 4 + r;
                if (edge) vv = (kg <= qg) ? vv : -INFINITY;
                pv[r] = __builtin_amdgcn_exp2f(vv);
                lsum += pv[r];
            }
            pk[kt][0] = cvt2(pv[0], pv[1]);
            pk[kt][1] = cvt2(pv[2], pv[3]);
        }

        // redistribute to A-frag P[q=q15][k=ks2*32+hi*8+j] via permlane; PV
        #pragma unroll
        for (int ks2 = 0; ks2 < 2; ++ks2) {
            unsigned a0 = pk[2 * ks2][0],     a1 = pk[2 * ks2][1];
            unsigned b0 = pk[2 * ks2 + 1][0], b1 = pk[2 * ks2 + 1][1];
            pl32swap(a0, b0);
            pl32swap(a1, b1);
            pl16swap(a0, b0);
            pl16swap(a1, b1);
            unsigned pw[4] = {a0, a1, b0, b1};
            bf16x8 pa;
            __builtin_memcpy(&pa, pw, 16);
            #pragma unroll
            for (int dt = 0; dt < 4; ++dt) {
                bf16x8 vf = *(const bf16x8*)&Vs[p][swz(dt * 16 + q15, ks2 * 64 + hi * 16)];
                accO[dt] = __builtin_amdgcn_mfma_f32_16x16x32_bf16(pa, vf, accO[dt], 0, 0, 0);
            }
        }

        __syncthreads();                          // next buffer staged + bufs free
        p ^= 1;
    }

    // l reduce over hi groups
    lsum += __shfl_xor(lsum, 16);
    lsum += __shfl_xor(lsum, 32);

    // partial write: O slab [64q][64d] in BF16, l in fp32
    const size_t slot = (size_t)b * 288 + pb8(qi) + sl;
    unsigned short* pO = PwsO + slot * PARTO_E;
    #pragma unroll
    for (int dt = 0; dt < 4; ++dt)
        #pragma unroll
        for (int r = 0; r < 4; ++r)
            pO[(w * 16 + hi * 4 + r) * 64 + dt * 16 + q15] = bf16rne(accO[dt][r]);
    if (hi == 0) PwsL[slot * PARTL_E + w * 16 + q15] = lsum;
}

// ---------------------------------------------------------------------------
// Pass 2: sum <=8 bf16 slice partials ([64q][64d]), normalize by fp32 l,
// write O. 256 blocks.
// ---------------------------------------------------------------------------
__global__ __launch_bounds__(256) void attn_merge_kernel(
    const unsigned short* __restrict__ PwsO, const float* __restrict__ PwsL,
    float* __restrict__ O)
{
    const int tid = threadIdx.x;
    const int b   = blockIdx.x & 3;
    const int qi  = blockIdx.x >> 2;
    const int np  = (qi + 8) >> 3;                // ceil((qi+1)/8) <= 8
    const size_t slot0 = (size_t)b * 288 + pb8(qi);
    const unsigned short* baseO = PwsO + slot0 * PARTO_E;
    const float* baseL = PwsL + slot0 * PARTL_E;

    const int q  = tid >> 2;                      // 0..63
    const int dg = (tid & 3) * 16;                // 0,16,32,48

    float s[16];
    #pragma unroll
    for (int i = 0; i < 16; ++i) s[i] = 0.f;
    float L = 0.f;
    for (int pp = 0; pp < np; ++pp) {
        const unsigned short* sp = baseO + (size_t)pp * PARTO_E + q * 64 + dg;
        uint4 v0 = *(const uint4*)sp;             // 8 bf16
        uint4 v1 = *(const uint4*)(sp + 8);       // 8 bf16
        const unsigned uu[8] = {v0.x, v0.y, v0.z, v0.w, v1.x, v1.y, v1.z, v1.w};
        #pragma unroll
        for (int i = 0; i < 8; ++i) {
            s[2*i]     += __uint_as_float(uu[i] << 16);
            s[2*i + 1] += __uint_as_float(uu[i] & 0xFFFF0000u);
        }
        L += baseL[(size_t)pp * PARTL_E + q];
    }
    const float rL = 1.0f / L;
    float* dst = O + ((size_t)b * N_ + qi * 64 + q) * D_ + dg;
    #pragma unroll
    for (int i = 0; i < 4; ++i)
        *(float4*)(dst + i * 4) = make_float4(s[4*i] * rL, s[4*i+1] * rL,
                                              s[4*i+2] * rL, s[4*i+3] * rL);
}

// ---------------------------------------------------------------------------
extern "C" void kernel_launch(void* const* d_in, const int* in_sizes, int n_in,
                              void* d_out, int out_size, void* d_ws, size_t ws_size,
                              hipStream_t stream)
{
    const float* x  = (const float*)d_in[0];
    const float* Wk = (const float*)d_in[1];
    const float* Wq = (const float*)d_in[2];
    const float* Wv = (const float*)d_in[3];
    float* O = (float*)d_out;

    const size_t per = (size_t)4 * N_ * D_;       // 1M bf16 elements each
    unsigned short* Kb = (unsigned short*)d_ws;
    unsigned short* Qb = Kb + per;
    unsigned short* Vt = Qb + per;
    unsigned short* PwsO = Vt + per;              // 288*4 slabs x 4096 bf16
    float* PwsL = (float*)(PwsO + (size_t)288 * 4 * PARTO_E);

    proj_kernel<<<dim3(4 * N_ / 64), 512, 0, stream>>>(x, Wk, Wq, Wv, Kb, Qb, Vt);
    attn_part_kernel<<<dim3(1152), 256, 0, stream>>>(Qb, Kb, Vt, PwsO, PwsL);
    attn_merge_kernel<<<dim3(256), 256, 0, stream>>>(PwsO, PwsL, O);
}